// Round 8
// baseline (603.310 us; speedup 1.0000x reference)
//
#include <hip/hip_runtime.h>

typedef unsigned long long u64;
typedef unsigned int u32;
typedef unsigned short ushort_t;

using f32x16 = __attribute__((ext_vector_type(16))) float;
using f32x4  = __attribute__((ext_vector_type(4))) float;
using short8 = __attribute__((ext_vector_type(8))) short;

#define NB 8
#define NPIX 65536
#define CAND_CAP 65536

// monotone float<->uint order-preserving encoding
__device__ __forceinline__ u32 fsort(float f){
  u32 u = __float_as_uint(f);
  return (u & 0x80000000u) ? ~u : (u | 0x80000000u);
}
__device__ __forceinline__ float funsort(u32 s){
  u32 u = (s & 0x80000000u) ? (s ^ 0x80000000u) : ~s;
  return __uint_as_float(u);
}
// round-to-nearest-even f32 -> bf16 bits
__device__ __forceinline__ u32 rneb(float f){
  u32 x = __float_as_uint(f);
  return (x + 0x7fffu + ((x >> 16) & 1u)) >> 16;
}
__device__ __forceinline__ float bf2f(u32 h){ return __uint_as_float(h << 16); }

// ---------------- prep: filter fragments (bf16 hi/lo), corner f32, priorR ----
// A-frag (main): [fy 0..32][kc 0..1][dt 0..1][lane][j 0..7]
//   d = dt*32 + (lane&31); fx = 16*kc + 8*(lane>>5) + j
// A-frag (column): [kc][dt][lane][j]: fy = 16*kc + 8*(lane>>5) + j, fx = 32 (hi only)
// fcorner/priorR: [dt][lane][reg]: d = dt*32 + (reg&3) + 8*(reg>>2) + 4*(lane>>5)
__global__ __launch_bounds__(256) void prep_kernel(
    const float* __restrict__ filt, const float* __restrict__ prior,
    ushort_t* __restrict__ afh, ushort_t* __restrict__ afl,
    ushort_t* __restrict__ acolh, float* __restrict__ fcorner,
    float* __restrict__ priorR, u32* __restrict__ ncand)
{
  int t = blockIdx.x * 256 + threadIdx.x;   // 16384 threads
  if (t == 0) *ncand = 0u;
  for (int i = t; i < 67584; i += 16384){
    int j = i & 7; int fidx = i >> 3; int lane = fidx & 63; int rest = fidx >> 6;
    int dt = rest & 1; int kc = (rest >> 1) & 1; int fy = rest >> 2;
    int d = dt * 32 + (lane & 31);
    int fx = 16 * kc + 8 * (lane >> 5) + j;
    float v = filt[d * 1089 + fy * 33 + fx];
    u32 hb = rneb(v);
    afh[i] = (ushort_t)hb;
    afl[i] = (ushort_t)rneb(v - bf2f(hb));
  }
  for (int i = t; i < 2048; i += 16384){
    int j = i & 7; int fidx = i >> 3; int lane = fidx & 63; int rest = fidx >> 6;
    int dt = rest & 1; int kc = rest >> 1;
    int d = dt * 32 + (lane & 31);
    int fy = 16 * kc + 8 * (lane >> 5) + j;
    acolh[i] = (ushort_t)rneb(filt[d * 1089 + fy * 33 + 32]);
  }
  for (int i = t; i < 2048; i += 16384){
    int reg = i & 15; int rest = i >> 4; int lane = rest & 63; int dt = rest >> 6;
    int d = dt * 32 + (reg & 3) + 8 * (reg >> 2) + 4 * (lane >> 5);
    fcorner[i] = filt[d * 1089 + 1088];
    priorR[i] = prior[d];
  }
}

// ---------------- conv via MFMA (split bf16) --------------------------------
__device__ __forceinline__ u32 funnel(u32 hi, u32 lo, int sh){
  return (u32)((((u64)hi << 32) | (u64)lo) >> sh);
}
template<int J>
__device__ __forceinline__ short8 extractf(uint4 P0, uint4 P1, int sh){
  u32 W[8] = {P0.x, P0.y, P0.z, P0.w, P1.x, P1.y, P1.z, P1.w};
  uint4 t;
  t.x = funnel(W[J + 1], W[J + 0], sh);
  t.y = funnel(W[J + 2], W[J + 1], sh);
  t.z = funnel(W[J + 3], W[J + 2], sh);
  t.w = funnel(W[J + 4], W[J + 3], sh);
  return __builtin_bit_cast(short8, t);
}
__device__ __forceinline__ f32x16 zero16(){
  f32x16 v;
  #pragma unroll
  for (int i = 0; i < 16; ++i) v[i] = 0.f;
  return v;
}

// LDS: hi rows [40][256] bf16 at byte 0 (row stride 512B), lo at byte 20480.
template<int J>
__device__ __forceinline__ void conv_body(
    const char* ldsc, const ushort_t* lds16, int w, int l, int tX,
    const short8* __restrict__ afh8, const short8* __restrict__ afl8,
    const short8* __restrict__ acol8, const f32x4* __restrict__ fcp,
    const f32x4* __restrict__ prp, u64* __restrict__ pb, int sh)
{
  const int c = l & 31, h = l >> 5;
  const int y0 = w;                 // 0..7; pixels y = y0 + 8c
  int cob0[2], cob1[2];
  #pragma unroll
  for (int kc = 0; kc < 2; ++kc){
    int yp = (y0 + 8 * c + 16 * kc + 8 * h - 16) & 255;
    int b0 = yp >> 3, b1 = (b0 + 1) & 31;
    cob0[kc] = b0 * 16; cob1[kc] = b1 * 16;
  }
  const int cc = (y0 + 8 * c + 16) & 255;   // column-pass / corner col

  for (int g0 = 0; g0 < 4; ++g0){
    const int r0 = g0 * 2;                  // rows r0, r0+1
    f32x16 acc[2][2];                       // [nr][dt]
    #pragma unroll
    for (int nr = 0; nr < 2; ++nr)
      #pragma unroll
      for (int dt = 0; dt < 2; ++dt) acc[nr][dt] = zero16();

    int aH0[2], aH1[2];
    #pragma unroll
    for (int kc = 0; kc < 2; ++kc){ aH0[kc] = r0 * 512 + cob0[kc]; aH1[kc] = r0 * 512 + cob1[kc]; }

    short8 a0h[2][2], a0l[2][2], a1h[2][2], a1l[2][2];
    #pragma unroll
    for (int kc = 0; kc < 2; ++kc)
      #pragma unroll
      for (int dt = 0; dt < 2; ++dt){
        a0h[kc][dt] = afh8[((0 * 2 + kc) * 2 + dt) * 64 + l];
        a0l[kc][dt] = afl8[((0 * 2 + kc) * 2 + dt) * 64 + l];
      }

#define CPH(AH, AL, NH, NL, FYP, DOPF)                                        \
    {                                                                         \
      if (DOPF){                                                              \
        _Pragma("unroll")                                                     \
        for (int kc = 0; kc < 2; ++kc)                                        \
          _Pragma("unroll")                                                   \
          for (int dt = 0; dt < 2; ++dt){                                     \
            NH[kc][dt] = afh8[(((FYP) * 2 + kc) * 2 + dt) * 64 + l];          \
            NL[kc][dt] = afl8[(((FYP) * 2 + kc) * 2 + dt) * 64 + l];          \
          }                                                                   \
      }                                                                       \
      short8 Bh[2][2], Bl[2][2];                                              \
      _Pragma("unroll")                                                       \
      for (int nr = 0; nr < 2; ++nr)                                          \
        _Pragma("unroll")                                                     \
        for (int kc = 0; kc < 2; ++kc){                                       \
          uint4 p0 = *(const uint4*)(ldsc + aH0[kc] + nr * 512);              \
          uint4 p1 = *(const uint4*)(ldsc + aH1[kc] + nr * 512);              \
          uint4 q0 = *(const uint4*)(ldsc + aH0[kc] + nr * 512 + 20480);      \
          uint4 q1 = *(const uint4*)(ldsc + aH1[kc] + nr * 512 + 20480);      \
          Bh[nr][kc] = extractf<J>(p0, p1, sh);                               \
          Bl[nr][kc] = extractf<J>(q0, q1, sh);                               \
        }                                                                     \
      _Pragma("unroll")                                                       \
      for (int nr = 0; nr < 2; ++nr)                                          \
        _Pragma("unroll")                                                     \
        for (int kc = 0; kc < 2; ++kc)                                        \
          _Pragma("unroll")                                                   \
          for (int dt = 0; dt < 2; ++dt){                                     \
            acc[nr][dt] = __builtin_amdgcn_mfma_f32_32x32x16_bf16(            \
                AH[kc][dt], Bh[nr][kc], acc[nr][dt], 0, 0, 0);                \
            acc[nr][dt] = __builtin_amdgcn_mfma_f32_32x32x16_bf16(            \
                AH[kc][dt], Bl[nr][kc], acc[nr][dt], 0, 0, 0);                \
            acc[nr][dt] = __builtin_amdgcn_mfma_f32_32x32x16_bf16(            \
                AL[kc][dt], Bh[nr][kc], acc[nr][dt], 0, 0, 0);                \
          }                                                                   \
      _Pragma("unroll")                                                       \
      for (int kc = 0; kc < 2; ++kc){ aH0[kc] += 512; aH1[kc] += 512; }       \
    }

    #pragma unroll 1
    for (int fy2 = 0; fy2 < 32; fy2 += 2){
      CPH(a0h, a0l, a1h, a1l, fy2 + 1, true)
      CPH(a1h, a1l, a0h, a0l, fy2 + 2, true)   // fy2+2 <= 32
    }
    CPH(a0h, a0l, a1h, a1l, 0, false)          // fy = 32
#undef CPH

    // column pass: fx = 32, k = fy (0..31), hi-only
    #pragma unroll
    for (int nr = 0; nr < 2; ++nr){
      #pragma unroll
      for (int kc = 0; kc < 2; ++kc){
        int base = (r0 + nr + 16 * kc + 8 * h) * 512 + cc * 2;
        u32 v0 = *(const ushort_t*)(ldsc + base + 0 * 512);
        u32 v1 = *(const ushort_t*)(ldsc + base + 1 * 512);
        u32 v2 = *(const ushort_t*)(ldsc + base + 2 * 512);
        u32 v3 = *(const ushort_t*)(ldsc + base + 3 * 512);
        u32 v4 = *(const ushort_t*)(ldsc + base + 4 * 512);
        u32 v5 = *(const ushort_t*)(ldsc + base + 5 * 512);
        u32 v6 = *(const ushort_t*)(ldsc + base + 6 * 512);
        u32 v7 = *(const ushort_t*)(ldsc + base + 7 * 512);
        uint4 t;
        t.x = v0 | (v1 << 16); t.y = v2 | (v3 << 16);
        t.z = v4 | (v5 << 16); t.w = v6 | (v7 << 16);
        short8 Bc = __builtin_bit_cast(short8, t);
        #pragma unroll
        for (int dt = 0; dt < 2; ++dt)
          acc[nr][dt] = __builtin_amdgcn_mfma_f32_32x32x16_bf16(
              acol8[(kc * 2 + dt) * 64 + l], Bc, acc[nr][dt], 0, 0, 0);
      }
    }

    // corner (fy=32, fx=32) exact f32 + prior-scale + per-pixel best + store.
    // lanes l and l+32 hold the same output column but complementary d-halves
    // -> combine via shfl_xor(32); single writer (h==0).
    #pragma unroll
    for (int nr = 0; nr < 2; ++nr){
      u32 hv = lds16[(r0 + nr + 32) * 256 + cc];
      u32 lv = lds16[10240 + (r0 + nr + 32) * 256 + cc];
      float cv = bf2f(hv) + bf2f(lv);
      float bv = -3e38f; int bd = 0;
      #pragma unroll
      for (int dt = 0; dt < 2; ++dt){
        #pragma unroll
        for (int q = 0; q < 4; ++q){
          f32x4 fc4 = fcp[(dt * 64 + l) * 4 + q];
          f32x4 pr4 = prp[(dt * 64 + l) * 4 + q];
          #pragma unroll
          for (int e = 0; e < 4; ++e){
            int reg = q * 4 + e;
            float s = (acc[nr][dt][reg] + fc4[e] * cv) * pr4[e];
            int d = dt * 32 + e + 8 * q + 4 * h;
            if (s > bv || (s == bv && d < bd)){ bv = s; bd = d; }
          }
        }
      }
      int x = tX + r0 + nr;
      int y = y0 + 8 * c;
      u64 key = ((u64)fsort(bv) << 32) | (u64)(63 - bd);
      u64 other = __shfl_xor(key, 32);     // combine the two d-halves
      if (other > key) key = other;
      if (h == 0) pb[(x << 8) | y] = key;  // single writer per pixel
    }
  }
}

__global__ __launch_bounds__(512) void conv_mfma(
    const float* __restrict__ input,
    const ushort_t* __restrict__ afh, const ushort_t* __restrict__ afl,
    const ushort_t* __restrict__ acolh, const float* __restrict__ fcorner,
    const float* __restrict__ priorR, u64* __restrict__ packed)
{
  __shared__ ushort_t lds[20480];          // hi [40][256], lo at +10240
  const int bS = blockIdx.x;               // stripe 0..31
  const int b  = blockIdx.y;
  const int tX = bS * 8;
  const int tid = threadIdx.x;

  const float* inb = input + b * NPIX;
  u32* ldsw = (u32*)lds;
  for (int k = tid; k < 2560; k += 512){   // 40 rows * 64 float4
    int r = k >> 6, c4 = k & 63;
    int gx = (tX - 16 + r) & 255;
    float4 v = *(const float4*)(inb + (gx << 8) + (c4 << 2));
    u32 h0 = rneb(v.x), h1 = rneb(v.y), h2 = rneb(v.z), h3 = rneb(v.w);
    u32 l0 = rneb(v.x - bf2f(h0)), l1 = rneb(v.y - bf2f(h1));
    u32 l2 = rneb(v.z - bf2f(h2)), l3 = rneb(v.w - bf2f(h3));
    int wi = r * 128 + c4 * 2;
    ldsw[wi]     = h0 | (h1 << 16);
    ldsw[wi + 1] = h2 | (h3 << 16);
    ldsw[5120 + wi]     = l0 | (l1 << 16);
    ldsw[5120 + wi + 1] = l2 | (l3 << 16);
  }
  __syncthreads();

  const int w = tid >> 6, l = tid & 63;
  u64* pb = packed + b * NPIX;
  const int sh = 16 * (w & 1);
  const char* ldsc = (const char*)lds;
  const short8* afh8 = (const short8*)afh;
  const short8* afl8 = (const short8*)afl;
  const short8* acol8 = (const short8*)acolh;
  const f32x4* fcp = (const f32x4*)fcorner;
  const f32x4* prp = (const f32x4*)priorR;

  switch ((w >> 1) & 3){
    case 0: conv_body<0>(ldsc, lds, w, l, tX, afh8, afl8, acol8, fcp, prp, pb, sh); break;
    case 1: conv_body<1>(ldsc, lds, w, l, tX, afh8, afl8, acol8, fcp, prp, pb, sh); break;
    case 2: conv_body<2>(ldsc, lds, w, l, tX, afh8, afl8, acol8, fcp, prp, pb, sh); break;
    default: conv_body<3>(ldsc, lds, w, l, tX, afh8, afl8, acol8, fcp, prp, pb, sh); break;
  }
}

// ---------------- per-batch max + candidate collection (fused) --------------
__global__ __launch_bounds__(1024) void bc_kernel(const u64* __restrict__ packed,
    u32* __restrict__ ncand, u32* __restrict__ cand){
  const int b = blockIdx.x, tid = threadIdx.x;
  const u32* ph = (const u32*)(packed + b * NPIX);   // hi word at odd index
  u32 m = 0;
  for (int k = tid; k < NPIX; k += 1024) m = max(m, ph[2 * k + 1]);
  __shared__ u32 red[1024];
  red[tid] = m; __syncthreads();
  for (int s = 512; s > 0; s >>= 1){
    if (tid < s) red[tid] = max(red[tid], red[tid + s]);
    __syncthreads();
  }
  float M = funsort(red[0]);
  u32 tu = fsort(M - 44.0f);
  for (int k = tid; k < NPIX; k += 1024){
    u32 v = ph[2 * k + 1];
    if (v >= tu){
      u32 slot = atomicAdd(ncand, 1u);
      if (slot < CAND_CAP) cand[slot] = ((u32)b << 16) | (u32)k;
    }
  }
}

// ---------------- exact fp32 recompute for candidates, patch map ------------
__global__ __launch_bounds__(64) void rerank_kernel(
    const float* __restrict__ input, const float* __restrict__ filt,
    const float* __restrict__ prior, const u32* __restrict__ ncand,
    const u32* __restrict__ cand, u64* __restrict__ packed)
{
  const int lane = threadIdx.x;            // = d
  int n = (int)min(*ncand, (u32)CAND_CAP);
  const float* fb = filt + lane * 1089;
  float pv = prior[lane];
  for (int i = blockIdx.x; i < n; i += 1024){
    u32 v = cand[i];
    int b = v >> 16, p = v & 0xffff;
    int px = p >> 8, py = p & 255;
    int yc = py - 16;
    float s = 0.f;
    for (int fy = 0; fy < 33; ++fy){
      const float* ir = input + b * NPIX + (((px + fy - 16) & 255) << 8);
      const float* fr = fb + fy * 33;
      for (int fx = 0; fx < 33; ++fx)
        s = fmaf(fr[fx], ir[(yc + fx) & 255], s);
    }
    u64 key = ((u64)fsort(s * pv) << 32) | (u64)(63 - lane);
    #pragma unroll
    for (int off = 32; off; off >>= 1){
      u64 o = __shfl_down(key, off);
      if (o > key) key = o;
    }
    if (lane == 0) packed[b * NPIX + p] = key;
  }
}

// ---------------- fused greedy loop: one block per batch, 10 iterations -----
// u map lives in registers (u[128] per thread, fully static indexing); only
// the packed hi-words (256KB/batch, L2-resident) are re-read each iteration.
__global__ __launch_bounds__(512) void greedy_kernel(
    const u64* __restrict__ packed, const float* __restrict__ prior,
    float* __restrict__ out)
{
  const int b = blockIdx.x;
  const int tid = threadIdx.x;
  const u64* pb = packed + b * NPIX;
  const u32* ph = (const u32*)pb;

  float u[128];
  #pragma unroll
  for (int i = 0; i < 128; ++i){
    int p = i * 512 + tid;
    int x = p >> 8, y = p & 255;
    u[i] = (x >= 16 && x < 240 && y >= 16 && y < 240) ? 1.0f : 0.0f;
  }

  __shared__ float rmax[512]; __shared__ int rid[512]; __shared__ float rum[512];
  __shared__ int spx, spy;
  if (tid == 0){ spx = -100000; spy = -100000; }
  __syncthreads();

  for (int t = 0; t < 10; ++t){
    const int px = spx, py = spy;
    float lmax = -3e38f; int lidx = 0; float lu = 0.f;
    #pragma unroll
    for (int i = 0; i < 128; ++i){
      int p = i * 512 + tid;
      int x = p >> 8, y = p & 255;
      float dx = (float)(x - px), dy = (float)(y - py);
      float d2 = dx * dx + dy * dy;
      float tm = 1.f - __expf(d2 * -0.03125f);     // 1/(2*sigma^2), sigma=4
      if (d2 <= 16.f) tm = 0.f;                    // hard cutout r=4
      float uu = u[i] * tm;
      u[i] = uu;
      float bvv = funsort(ph[2 * p + 1]);
      float s = bvv * uu;
      if (s > lmax || (s == lmax && p < lidx)){ lmax = s; lidx = p; }
      if (uu > lu) lu = uu;
    }
    rmax[tid] = lmax; rid[tid] = lidx; rum[tid] = lu;
    __syncthreads();
    for (int s2 = 256; s2 > 0; s2 >>= 1){
      if (tid < s2){
        float v2 = rmax[tid + s2]; int i2 = rid[tid + s2];
        if (v2 > rmax[tid] || (v2 == rmax[tid] && i2 < rid[tid])){ rmax[tid] = v2; rid[tid] = i2; }
        if (rum[tid + s2] > rum[tid]) rum[tid] = rum[tid + s2];
      }
      __syncthreads();
    }
    if (tid == 0){
      int id = rid[0];
      float v = rmax[0], um = rum[0];
      u64 key = pb[id];
      int d = 63 - (int)(key & 63ull);
      float bvv = funsort((u32)(key >> 32));
      int x = id >> 8, y = id & 255;
      out[b * 30 + t * 3 + 0] = (float)d;     // position_found [B,10,3]
      out[b * 30 + t * 3 + 1] = (float)x;
      out[b * 30 + t * 3 + 2] = (float)y;
      out[240 + b * 20 + t * 2 + 0] = v / um;        // ov0
      out[240 + b * 20 + t * 2 + 1] = bvv / prior[d];// ov1
      spx = x; spy = y;
    }
    __syncthreads();
  }
}

extern "C" void kernel_launch(void* const* d_in, const int* in_sizes, int n_in,
                              void* d_out, int out_size, void* d_ws, size_t ws_size,
                              hipStream_t stream)
{
  const float* input = (const float*)d_in[0];
  const float* filt  = (const float*)d_in[1];
  const float* prior = (const float*)d_in[3];
  float* out = (float*)d_out;

  char* ws = (char*)d_ws;
  u64*      packed  = (u64*)(ws);                    // 4,194,304
  u32*      ncand   = (u32*)  (ws + 4194304);
  ushort_t* afh     = (ushort_t*)(ws + 4194368);     // 135168
  ushort_t* afl     = (ushort_t*)(ws + 4329536);     // 135168
  ushort_t* acolh   = (ushort_t*)(ws + 4464704);     // 4096
  float*    fcorner = (float*)(ws + 4468800);        // 8192
  float*    priorR  = (float*)(ws + 4476992);        // 8192
  u32*      cand    = (u32*)  (ws + 4485184);        // 262144

  prep_kernel<<<64, 256, 0, stream>>>(filt, prior, afh, afl, acolh, fcorner, priorR, ncand);
  conv_mfma<<<dim3(32, NB), 512, 0, stream>>>(input, afh, afl, acolh, fcorner, priorR, packed);
  bc_kernel<<<NB, 1024, 0, stream>>>(packed, ncand, cand);
  rerank_kernel<<<1024, 64, 0, stream>>>(input, filt, prior, ncand, cand, packed);
  greedy_kernel<<<NB, 512, 0, stream>>>(packed, prior, out);
}

// Round 9
// 385.990 us; speedup vs baseline: 1.5630x; 1.5630x over previous
//
#include <hip/hip_runtime.h>

typedef unsigned long long u64;
typedef unsigned int u32;
typedef unsigned short ushort_t;

using f32x16 = __attribute__((ext_vector_type(16))) float;
using f32x4  = __attribute__((ext_vector_type(4))) float;
using short8 = __attribute__((ext_vector_type(8))) short;

#define NB 8
#define NPIX 65536
#define CAND_CAP 65536

// monotone float<->uint order-preserving encoding
__device__ __forceinline__ u32 fsort(float f){
  u32 u = __float_as_uint(f);
  return (u & 0x80000000u) ? ~u : (u | 0x80000000u);
}
__device__ __forceinline__ float funsort(u32 s){
  u32 u = (s & 0x80000000u) ? (s ^ 0x80000000u) : ~s;
  return __uint_as_float(u);
}
// round-to-nearest-even f32 -> bf16 bits
__device__ __forceinline__ u32 rneb(float f){
  u32 x = __float_as_uint(f);
  return (x + 0x7fffu + ((x >> 16) & 1u)) >> 16;
}
__device__ __forceinline__ float bf2f(u32 h){ return __uint_as_float(h << 16); }

// ---------------- prep: filter fragments (bf16 hi/lo), corner f32, priorR ----
// A-frag (main): [fy 0..32][kc 0..1][dt 0..1][lane][j 0..7]
//   d = dt*32 + (lane&31); fx = 16*kc + 8*(lane>>5) + j
// A-frag (column): [kc][dt][lane][j]: fy = 16*kc + 8*(lane>>5) + j, fx = 32 (hi only)
// fcorner/priorR: [dt][lane][reg]: d = dt*32 + (reg&3) + 8*(reg>>2) + 4*(lane>>5)
__global__ __launch_bounds__(256) void prep_kernel(
    const float* __restrict__ filt, const float* __restrict__ prior,
    ushort_t* __restrict__ afh, ushort_t* __restrict__ afl,
    ushort_t* __restrict__ acolh, float* __restrict__ fcorner,
    float* __restrict__ priorR, u32* __restrict__ ncand)
{
  int t = blockIdx.x * 256 + threadIdx.x;   // 16384 threads
  if (t == 0) *ncand = 0u;
  for (int i = t; i < 67584; i += 16384){
    int j = i & 7; int fidx = i >> 3; int lane = fidx & 63; int rest = fidx >> 6;
    int dt = rest & 1; int kc = (rest >> 1) & 1; int fy = rest >> 2;
    int d = dt * 32 + (lane & 31);
    int fx = 16 * kc + 8 * (lane >> 5) + j;
    float v = filt[d * 1089 + fy * 33 + fx];
    u32 hb = rneb(v);
    afh[i] = (ushort_t)hb;
    afl[i] = (ushort_t)rneb(v - bf2f(hb));
  }
  for (int i = t; i < 2048; i += 16384){
    int j = i & 7; int fidx = i >> 3; int lane = fidx & 63; int rest = fidx >> 6;
    int dt = rest & 1; int kc = rest >> 1;
    int d = dt * 32 + (lane & 31);
    int fy = 16 * kc + 8 * (lane >> 5) + j;
    acolh[i] = (ushort_t)rneb(filt[d * 1089 + fy * 33 + 32]);
  }
  for (int i = t; i < 2048; i += 16384){
    int reg = i & 15; int rest = i >> 4; int lane = rest & 63; int dt = rest >> 6;
    int d = dt * 32 + (reg & 3) + 8 * (reg >> 2) + 4 * (lane >> 5);
    fcorner[i] = filt[d * 1089 + 1088];
    priorR[i] = prior[d];
  }
}

// ---------------- conv via MFMA (split bf16) --------------------------------
__device__ __forceinline__ u32 funnel(u32 hi, u32 lo, int sh){
  return (u32)((((u64)hi << 32) | (u64)lo) >> sh);
}
template<int J>
__device__ __forceinline__ short8 extractf(uint4 P0, uint4 P1, int sh){
  u32 W[8] = {P0.x, P0.y, P0.z, P0.w, P1.x, P1.y, P1.z, P1.w};
  uint4 t;
  t.x = funnel(W[J + 1], W[J + 0], sh);
  t.y = funnel(W[J + 2], W[J + 1], sh);
  t.z = funnel(W[J + 3], W[J + 2], sh);
  t.w = funnel(W[J + 4], W[J + 3], sh);
  return __builtin_bit_cast(short8, t);
}
__device__ __forceinline__ f32x16 zero16(){
  f32x16 v;
  #pragma unroll
  for (int i = 0; i < 16; ++i) v[i] = 0.f;
  return v;
}

// LDS: hi rows [36][256] bf16 at byte 0 (row stride 512B), lo at byte 18432.
// Block = 4-row x 256-col output stripe (R9: was 8 rows; 512 blocks -> 2/CU).
template<int J>
__device__ __forceinline__ void conv_body(
    const char* ldsc, const ushort_t* lds16, int w, int l, int tX,
    const short8* __restrict__ afh8, const short8* __restrict__ afl8,
    const short8* __restrict__ acol8, const f32x4* __restrict__ fcp,
    const f32x4* __restrict__ prp, u64* __restrict__ pb, int sh)
{
  const int c = l & 31, h = l >> 5;
  const int y0 = w;                 // 0..7; pixels y = y0 + 8c
  int cob0[2], cob1[2];
  #pragma unroll
  for (int kc = 0; kc < 2; ++kc){
    int yp = (y0 + 8 * c + 16 * kc + 8 * h - 16) & 255;
    int b0 = yp >> 3, b1 = (b0 + 1) & 31;
    cob0[kc] = b0 * 16; cob1[kc] = b1 * 16;
  }
  const int cc = (y0 + 8 * c + 16) & 255;   // column-pass / corner col

  for (int g0 = 0; g0 < 2; ++g0){
    const int r0 = g0 * 2;                  // rows r0, r0+1
    f32x16 acc[2][2];                       // [nr][dt]
    #pragma unroll
    for (int nr = 0; nr < 2; ++nr)
      #pragma unroll
      for (int dt = 0; dt < 2; ++dt) acc[nr][dt] = zero16();

    int aH0[2], aH1[2];
    #pragma unroll
    for (int kc = 0; kc < 2; ++kc){ aH0[kc] = r0 * 512 + cob0[kc]; aH1[kc] = r0 * 512 + cob1[kc]; }

    short8 a0h[2][2], a0l[2][2], a1h[2][2], a1l[2][2];
    #pragma unroll
    for (int kc = 0; kc < 2; ++kc)
      #pragma unroll
      for (int dt = 0; dt < 2; ++dt){
        a0h[kc][dt] = afh8[((0 * 2 + kc) * 2 + dt) * 64 + l];
        a0l[kc][dt] = afl8[((0 * 2 + kc) * 2 + dt) * 64 + l];
      }

#define CPH(AH, AL, NH, NL, FYP, DOPF)                                        \
    {                                                                         \
      if (DOPF){                                                              \
        _Pragma("unroll")                                                     \
        for (int kc = 0; kc < 2; ++kc)                                        \
          _Pragma("unroll")                                                   \
          for (int dt = 0; dt < 2; ++dt){                                     \
            NH[kc][dt] = afh8[(((FYP) * 2 + kc) * 2 + dt) * 64 + l];          \
            NL[kc][dt] = afl8[(((FYP) * 2 + kc) * 2 + dt) * 64 + l];          \
          }                                                                   \
      }                                                                       \
      short8 Bh[2][2], Bl[2][2];                                              \
      _Pragma("unroll")                                                       \
      for (int nr = 0; nr < 2; ++nr)                                          \
        _Pragma("unroll")                                                     \
        for (int kc = 0; kc < 2; ++kc){                                       \
          uint4 p0 = *(const uint4*)(ldsc + aH0[kc] + nr * 512);              \
          uint4 p1 = *(const uint4*)(ldsc + aH1[kc] + nr * 512);              \
          uint4 q0 = *(const uint4*)(ldsc + aH0[kc] + nr * 512 + 18432);      \
          uint4 q1 = *(const uint4*)(ldsc + aH1[kc] + nr * 512 + 18432);      \
          Bh[nr][kc] = extractf<J>(p0, p1, sh);                               \
          Bl[nr][kc] = extractf<J>(q0, q1, sh);                               \
        }                                                                     \
      _Pragma("unroll")                                                       \
      for (int nr = 0; nr < 2; ++nr)                                          \
        _Pragma("unroll")                                                     \
        for (int kc = 0; kc < 2; ++kc)                                        \
          _Pragma("unroll")                                                   \
          for (int dt = 0; dt < 2; ++dt){                                     \
            acc[nr][dt] = __builtin_amdgcn_mfma_f32_32x32x16_bf16(            \
                AH[kc][dt], Bh[nr][kc], acc[nr][dt], 0, 0, 0);                \
            acc[nr][dt] = __builtin_amdgcn_mfma_f32_32x32x16_bf16(            \
                AH[kc][dt], Bl[nr][kc], acc[nr][dt], 0, 0, 0);                \
            acc[nr][dt] = __builtin_amdgcn_mfma_f32_32x32x16_bf16(            \
                AL[kc][dt], Bh[nr][kc], acc[nr][dt], 0, 0, 0);                \
          }                                                                   \
      _Pragma("unroll")                                                       \
      for (int kc = 0; kc < 2; ++kc){ aH0[kc] += 512; aH1[kc] += 512; }       \
    }

    #pragma unroll 1
    for (int fy2 = 0; fy2 < 32; fy2 += 2){
      CPH(a0h, a0l, a1h, a1l, fy2 + 1, true)
      CPH(a1h, a1l, a0h, a0l, fy2 + 2, true)   // fy2+2 <= 32
    }
    CPH(a0h, a0l, a1h, a1l, 0, false)          // fy = 32
#undef CPH

    // column pass: fx = 32, k = fy (0..31), hi-only
    #pragma unroll
    for (int nr = 0; nr < 2; ++nr){
      #pragma unroll
      for (int kc = 0; kc < 2; ++kc){
        int base = (r0 + nr + 16 * kc + 8 * h) * 512 + cc * 2;
        u32 v0 = *(const ushort_t*)(ldsc + base + 0 * 512);
        u32 v1 = *(const ushort_t*)(ldsc + base + 1 * 512);
        u32 v2 = *(const ushort_t*)(ldsc + base + 2 * 512);
        u32 v3 = *(const ushort_t*)(ldsc + base + 3 * 512);
        u32 v4 = *(const ushort_t*)(ldsc + base + 4 * 512);
        u32 v5 = *(const ushort_t*)(ldsc + base + 5 * 512);
        u32 v6 = *(const ushort_t*)(ldsc + base + 6 * 512);
        u32 v7 = *(const ushort_t*)(ldsc + base + 7 * 512);
        uint4 t;
        t.x = v0 | (v1 << 16); t.y = v2 | (v3 << 16);
        t.z = v4 | (v5 << 16); t.w = v6 | (v7 << 16);
        short8 Bc = __builtin_bit_cast(short8, t);
        #pragma unroll
        for (int dt = 0; dt < 2; ++dt)
          acc[nr][dt] = __builtin_amdgcn_mfma_f32_32x32x16_bf16(
              acol8[(kc * 2 + dt) * 64 + l], Bc, acc[nr][dt], 0, 0, 0);
      }
    }

    // corner (fy=32, fx=32) exact f32 + prior-scale + per-pixel best + store.
    // lanes l and l+32 hold the same output column but complementary d-halves
    // -> combine via shfl_xor(32); single writer (h==0).
    #pragma unroll
    for (int nr = 0; nr < 2; ++nr){
      u32 hv = lds16[(r0 + nr + 32) * 256 + cc];
      u32 lv = lds16[9216 + (r0 + nr + 32) * 256 + cc];
      float cv = bf2f(hv) + bf2f(lv);
      float bv = -3e38f; int bd = 0;
      #pragma unroll
      for (int dt = 0; dt < 2; ++dt){
        #pragma unroll
        for (int q = 0; q < 4; ++q){
          f32x4 fc4 = fcp[(dt * 64 + l) * 4 + q];
          f32x4 pr4 = prp[(dt * 64 + l) * 4 + q];
          #pragma unroll
          for (int e = 0; e < 4; ++e){
            int reg = q * 4 + e;
            float s = (acc[nr][dt][reg] + fc4[e] * cv) * pr4[e];
            int d = dt * 32 + e + 8 * q + 4 * h;
            if (s > bv || (s == bv && d < bd)){ bv = s; bd = d; }
          }
        }
      }
      int x = tX + r0 + nr;
      int y = y0 + 8 * c;
      u64 key = ((u64)fsort(bv) << 32) | (u64)(63 - bd);
      u64 other = __shfl_xor(key, 32);     // combine the two d-halves
      if (other > key) key = other;
      if (h == 0) pb[(x << 8) | y] = key;  // single writer per pixel
    }
  }
}

__global__ __launch_bounds__(512) void conv_mfma(
    const float* __restrict__ input,
    const ushort_t* __restrict__ afh, const ushort_t* __restrict__ afl,
    const ushort_t* __restrict__ acolh, const float* __restrict__ fcorner,
    const float* __restrict__ priorR, u64* __restrict__ packed)
{
  __shared__ ushort_t lds[18432];          // hi [36][256], lo at ushort 9216
  const int bS = blockIdx.x;               // stripe 0..63
  const int b  = blockIdx.y;
  const int tX = bS * 4;
  const int tid = threadIdx.x;

  const float* inb = input + b * NPIX;
  u32* ldsw = (u32*)lds;
  for (int k = tid; k < 2304; k += 512){   // 36 rows * 64 float4
    int r = k >> 6, c4 = k & 63;
    int gx = (tX - 16 + r) & 255;
    float4 v = *(const float4*)(inb + (gx << 8) + (c4 << 2));
    u32 h0 = rneb(v.x), h1 = rneb(v.y), h2 = rneb(v.z), h3 = rneb(v.w);
    u32 l0 = rneb(v.x - bf2f(h0)), l1 = rneb(v.y - bf2f(h1));
    u32 l2 = rneb(v.z - bf2f(h2)), l3 = rneb(v.w - bf2f(h3));
    int wi = r * 128 + c4 * 2;
    ldsw[wi]     = h0 | (h1 << 16);
    ldsw[wi + 1] = h2 | (h3 << 16);
    ldsw[4608 + wi]     = l0 | (l1 << 16);
    ldsw[4608 + wi + 1] = l2 | (l3 << 16);
  }
  __syncthreads();

  const int w = tid >> 6, l = tid & 63;
  u64* pb = packed + b * NPIX;
  const int sh = 16 * (w & 1);
  const char* ldsc = (const char*)lds;
  const short8* afh8 = (const short8*)afh;
  const short8* afl8 = (const short8*)afl;
  const short8* acol8 = (const short8*)acolh;
  const f32x4* fcp = (const f32x4*)fcorner;
  const f32x4* prp = (const f32x4*)priorR;

  switch ((w >> 1) & 3){
    case 0: conv_body<0>(ldsc, lds, w, l, tX, afh8, afl8, acol8, fcp, prp, pb, sh); break;
    case 1: conv_body<1>(ldsc, lds, w, l, tX, afh8, afl8, acol8, fcp, prp, pb, sh); break;
    case 2: conv_body<2>(ldsc, lds, w, l, tX, afh8, afl8, acol8, fcp, prp, pb, sh); break;
    default: conv_body<3>(ldsc, lds, w, l, tX, afh8, afl8, acol8, fcp, prp, pb, sh); break;
  }
}

// ---------------- per-batch max + candidate collection (fused) --------------
__global__ __launch_bounds__(1024) void bc_kernel(const u64* __restrict__ packed,
    u32* __restrict__ ncand, u32* __restrict__ cand){
  const int b = blockIdx.x, tid = threadIdx.x;
  const u32* ph = (const u32*)(packed + b * NPIX);   // hi word at odd index
  u32 m = 0;
  for (int k = tid; k < NPIX; k += 1024) m = max(m, ph[2 * k + 1]);
  __shared__ u32 red[1024];
  red[tid] = m; __syncthreads();
  for (int s = 512; s > 0; s >>= 1){
    if (tid < s) red[tid] = max(red[tid], red[tid + s]);
    __syncthreads();
  }
  float M = funsort(red[0]);
  u32 tu = fsort(M - 44.0f);
  for (int k = tid; k < NPIX; k += 1024){
    u32 v = ph[2 * k + 1];
    if (v >= tu){
      u32 slot = atomicAdd(ncand, 1u);
      if (slot < CAND_CAP) cand[slot] = ((u32)b << 16) | (u32)k;
    }
  }
}

// ---------------- exact fp32 recompute for candidates, patch map ------------
__global__ __launch_bounds__(64) void rerank_kernel(
    const float* __restrict__ input, const float* __restrict__ filt,
    const float* __restrict__ prior, const u32* __restrict__ ncand,
    const u32* __restrict__ cand, u64* __restrict__ packed)
{
  const int lane = threadIdx.x;            // = d
  int n = (int)min(*ncand, (u32)CAND_CAP);
  const float* fb = filt + lane * 1089;
  float pv = prior[lane];
  for (int i = blockIdx.x; i < n; i += 1024){
    u32 v = cand[i];
    int b = v >> 16, p = v & 0xffff;
    int px = p >> 8, py = p & 255;
    int yc = py - 16;
    float s = 0.f;
    for (int fy = 0; fy < 33; ++fy){
      const float* ir = input + b * NPIX + (((px + fy - 16) & 255) << 8);
      const float* fr = fb + fy * 33;
      for (int fx = 0; fx < 33; ++fx)
        s = fmaf(fr[fx], ir[(yc + fx) & 255], s);
    }
    u64 key = ((u64)fsort(s * pv) << 32) | (u64)(63 - lane);
    #pragma unroll
    for (int off = 32; off; off >>= 1){
      u64 o = __shfl_down(key, off);
      if (o > key) key = o;
    }
    if (lane == 0) packed[b * NPIX + p] = key;
  }
}

// ---------------- fused greedy loop: incremental deadzone (R9) --------------
// Key facts (f32, round-to-nearest): 1-exp(-d2/32) == 1.0f exactly for
// d2 > 554.5 (exp < 2^-25), so each pick only perturbs a 49x49 patch; and
// 10 discs of ~1742px can't cover the 224x224 interior, so max(u) == 1.0f
// exactly every iteration -> reference's normalization is an exact no-op.
// Maintain only s = conv*prior*PRODUCT(tmap) in registers (s[64]/thread) +
// per-thread (max,argmax); clean threads' maxima stay valid (s only drops).
__global__ __launch_bounds__(1024) void greedy_kernel(
    const u64* __restrict__ packed, const float* __restrict__ prior,
    float* __restrict__ out)
{
  const int b = blockIdx.x;
  const int tid = threadIdx.x;
  const u64* pb = packed + b * NPIX;
  const u32* ph = (const u32*)pb;

  const int x = tid >> 2;                 // owned image row
  const int ybase = (tid & 3) << 6;       // 64-col segment
  const int pbase = (x << 8) + ybase;

  float s[64];
  const bool rowin = (x >= 16 && x < 240);
  #pragma unroll
  for (int i = 0; i < 64; ++i){
    int y = ybase + i;
    float bvv = funsort(ph[2 * (pbase + i) + 1]);
    s[i] = (rowin && y >= 16 && y < 240) ? bvv : 0.0f;
  }
  float tm = -3e38f; int tp = pbase;
  #pragma unroll
  for (int i = 0; i < 64; ++i){
    if (s[i] > tm){ tm = s[i]; tp = pbase + i; }
  }

  __shared__ float rv[1024]; __shared__ int rp[1024];
  __shared__ int spx, spy;
  if (tid == 0){ spx = -100000; spy = -100000; }
  __syncthreads();

  for (int t = 0; t < 10; ++t){
    const int px = spx, py = spy;
    if (px >= 0){
      int dxr = x - px;
      if (dxr >= -24 && dxr <= 24){
        int lo = py - 24 - ybase;
        int hi = py + 24 - ybase;
        if (lo < 64 && hi >= 0){
          float dx2 = (float)(dxr * dxr);
          tm = -3e38f; tp = pbase;
          #pragma unroll
          for (int i = 0; i < 64; ++i){
            if (i >= lo && i <= hi){
              float dy = (float)(ybase + i - py);
              float d2 = dx2 + dy * dy;
              float tmap = 1.f - __expf(d2 * -0.03125f);
              if (d2 <= 16.f) tmap = 0.f;
              s[i] *= tmap;
            }
            if (s[i] > tm){ tm = s[i]; tp = pbase + i; }
          }
        }
      }
    }
    rv[tid] = tm; rp[tid] = tp;
    __syncthreads();
    for (int s2 = 512; s2 > 0; s2 >>= 1){
      if (tid < s2){
        float v2 = rv[tid + s2]; int p2 = rp[tid + s2];
        if (v2 > rv[tid] || (v2 == rv[tid] && p2 < rp[tid])){ rv[tid] = v2; rp[tid] = p2; }
      }
      __syncthreads();
    }
    if (tid == 0){
      int id = rp[0];
      float v = rv[0];
      u64 key = pb[id];
      int d = 63 - (int)(key & 63ull);
      float bvv = funsort((u32)(key >> 32));
      int xx = id >> 8, yy = id & 255;
      out[b * 30 + t * 3 + 0] = (float)d;     // position_found [B,10,3]
      out[b * 30 + t * 3 + 1] = (float)xx;
      out[b * 30 + t * 3 + 2] = (float)yy;
      out[240 + b * 20 + t * 2 + 0] = v;             // ov0 (umax==1.0 exact)
      out[240 + b * 20 + t * 2 + 1] = bvv / prior[d];// ov1
      spx = xx; spy = yy;
    }
    __syncthreads();
  }
}

extern "C" void kernel_launch(void* const* d_in, const int* in_sizes, int n_in,
                              void* d_out, int out_size, void* d_ws, size_t ws_size,
                              hipStream_t stream)
{
  const float* input = (const float*)d_in[0];
  const float* filt  = (const float*)d_in[1];
  const float* prior = (const float*)d_in[3];
  float* out = (float*)d_out;

  char* ws = (char*)d_ws;
  u64*      packed  = (u64*)(ws);                    // 4,194,304
  u32*      ncand   = (u32*)  (ws + 4194304);
  ushort_t* afh     = (ushort_t*)(ws + 4194368);     // 135168
  ushort_t* afl     = (ushort_t*)(ws + 4329536);     // 135168
  ushort_t* acolh   = (ushort_t*)(ws + 4464704);     // 4096
  float*    fcorner = (float*)(ws + 4468800);        // 8192
  float*    priorR  = (float*)(ws + 4476992);        // 8192
  u32*      cand    = (u32*)  (ws + 4485184);        // 262144

  prep_kernel<<<64, 256, 0, stream>>>(filt, prior, afh, afl, acolh, fcorner, priorR, ncand);
  conv_mfma<<<dim3(64, NB), 512, 0, stream>>>(input, afh, afl, acolh, fcorner, priorR, packed);
  bc_kernel<<<NB, 1024, 0, stream>>>(packed, ncand, cand);
  rerank_kernel<<<1024, 64, 0, stream>>>(input, filt, prior, ncand, cand, packed);
  greedy_kernel<<<NB, 1024, 0, stream>>>(packed, prior, out);
}

// Round 10
// 226.726 us; speedup vs baseline: 2.6610x; 1.7025x over previous
//
#include <hip/hip_runtime.h>

typedef unsigned long long u64;
typedef unsigned int u32;
typedef unsigned short ushort_t;

using f32x16 = __attribute__((ext_vector_type(16))) float;
using f32x4  = __attribute__((ext_vector_type(4))) float;
using short8 = __attribute__((ext_vector_type(8))) short;

#define NB 8
#define NPIX 65536
#define CAND_CAP 65536
#define MARGIN 45.0f   // spread<=44 (proven by 3-term passes) + 2*eps(bf16~0.3)

// monotone float<->uint order-preserving encoding
__device__ __forceinline__ u32 fsort(float f){
  u32 u = __float_as_uint(f);
  return (u & 0x80000000u) ? ~u : (u | 0x80000000u);
}
__device__ __forceinline__ float funsort(u32 s){
  u32 u = (s & 0x80000000u) ? (s ^ 0x80000000u) : ~s;
  return __uint_as_float(u);
}
// round-to-nearest-even f32 -> bf16 bits
__device__ __forceinline__ u32 rneb(float f){
  u32 x = __float_as_uint(f);
  return (x + 0x7fffu + ((x >> 16) & 1u)) >> 16;
}
__device__ __forceinline__ float bf2f(u32 h){ return __uint_as_float(h << 16); }

// ---------------- prep: filter fragments (bf16 hi), corner f32, priorR ------
// A-frag (main): [fy 0..32][kc 0..1][dt 0..1][lane][j 0..7]
//   d = dt*32 + (lane&31); fx = 16*kc + 8*(lane>>5) + j
// A-frag (column): [kc][dt][lane][j]: fy = 16*kc + 8*(lane>>5) + j, fx = 32
// fcorner/priorR: [dt][lane][reg]: d = dt*32 + (reg&3) + 8*(reg>>2) + 4*(lane>>5)
__global__ __launch_bounds__(256) void prep_kernel(
    const float* __restrict__ filt, const float* __restrict__ prior,
    ushort_t* __restrict__ afh, ushort_t* __restrict__ acolh,
    float* __restrict__ fcorner, float* __restrict__ priorR,
    u32* __restrict__ ncand, u32* __restrict__ mmax)
{
  int t = blockIdx.x * 256 + threadIdx.x;   // 16384 threads
  if (t == 0) *ncand = 0u;
  if (t < 8) mmax[t] = 0u;
  for (int i = t; i < 67584; i += 16384){
    int j = i & 7; int fidx = i >> 3; int lane = fidx & 63; int rest = fidx >> 6;
    int dt = rest & 1; int kc = (rest >> 1) & 1; int fy = rest >> 2;
    int d = dt * 32 + (lane & 31);
    int fx = 16 * kc + 8 * (lane >> 5) + j;
    afh[i] = (ushort_t)rneb(filt[d * 1089 + fy * 33 + fx]);
  }
  for (int i = t; i < 2048; i += 16384){
    int j = i & 7; int fidx = i >> 3; int lane = fidx & 63; int rest = fidx >> 6;
    int dt = rest & 1; int kc = rest >> 1;
    int d = dt * 32 + (lane & 31);
    int fy = 16 * kc + 8 * (lane >> 5) + j;
    acolh[i] = (ushort_t)rneb(filt[d * 1089 + fy * 33 + 32]);
  }
  for (int i = t; i < 2048; i += 16384){
    int reg = i & 15; int rest = i >> 4; int lane = rest & 63; int dt = rest >> 6;
    int d = dt * 32 + (reg & 3) + 8 * (reg >> 2) + 4 * (lane >> 5);
    fcorner[i] = filt[d * 1089 + 1088];
    priorR[i] = prior[d];
  }
}

// ---------------- conv via MFMA (pure bf16 + exact rerank downstream) -------
__device__ __forceinline__ u32 funnel(u32 hi, u32 lo, int sh){
  return (u32)((((u64)hi << 32) | (u64)lo) >> sh);
}
template<int J>
__device__ __forceinline__ short8 extractf(uint4 P0, uint4 P1, int sh){
  u32 W[8] = {P0.x, P0.y, P0.z, P0.w, P1.x, P1.y, P1.z, P1.w};
  uint4 t;
  t.x = funnel(W[J + 1], W[J + 0], sh);
  t.y = funnel(W[J + 2], W[J + 1], sh);
  t.z = funnel(W[J + 3], W[J + 2], sh);
  t.w = funnel(W[J + 4], W[J + 3], sh);
  return __builtin_bit_cast(short8, t);
}
__device__ __forceinline__ f32x16 zero16(){
  f32x16 v;
  #pragma unroll
  for (int i = 0; i < 16; ++i) v[i] = 0.f;
  return v;
}

// LDS: hi rows [36][256] bf16, row stride 512B. Block = 4-row x 256-col stripe.
// R10: rolling 2-row raw-uint4 register window (parity slots, static idx);
// per fy only ONE new row is read from LDS (4 x ds_read_b128).
template<int J>
__device__ __forceinline__ void conv_body(
    const char* ldsc, const ushort_t* lds16, int w, int l, int tX,
    const short8* __restrict__ afh8, const short8* __restrict__ acol8,
    const f32x4* __restrict__ fcp, const f32x4* __restrict__ prp,
    u64* __restrict__ pb, int sh)
{
  const int c = l & 31, h = l >> 5;
  const int y0 = w;                 // 0..7; pixels y = y0 + 8c
  int cob0[2], cob1[2];
  #pragma unroll
  for (int kc = 0; kc < 2; ++kc){
    int yp = (y0 + 8 * c + 16 * kc + 8 * h - 16) & 255;
    int b0 = yp >> 3, b1 = (b0 + 1) & 31;
    cob0[kc] = b0 * 16; cob1[kc] = b1 * 16;
  }
  const int cc = (y0 + 8 * c + 16) & 255;   // column-pass / corner col

#define LA(DST, FY)                                                           \
  { _Pragma("unroll")                                                         \
    for (int kc = 0; kc < 2; ++kc)                                            \
      _Pragma("unroll")                                                       \
      for (int dt = 0; dt < 2; ++dt)                                          \
        DST[kc][dt] = afh8[(((FY) * 2 + kc) * 2 + dt) * 64 + l]; }

#define LW(S, ROWI)                                                           \
  { const char* rb_ = ldsc + (ROWI) * 512;                                    \
    s##S##k0p0 = *(const uint4*)(rb_ + cob0[0]);                              \
    s##S##k0p1 = *(const uint4*)(rb_ + cob1[0]);                              \
    s##S##k1p0 = *(const uint4*)(rb_ + cob0[1]);                              \
    s##S##k1p1 = *(const uint4*)(rb_ + cob1[1]); }

#define CPH(SA, SB, ACUR, ANXT, FYP, DOPF)                                    \
  { if (DOPF){ LA(ANXT, FYP) }                                                \
    short8 b0k0 = extractf<J>(s##SA##k0p0, s##SA##k0p1, sh);                  \
    short8 b0k1 = extractf<J>(s##SA##k1p0, s##SA##k1p1, sh);                  \
    short8 b1k0 = extractf<J>(s##SB##k0p0, s##SB##k0p1, sh);                  \
    short8 b1k1 = extractf<J>(s##SB##k1p0, s##SB##k1p1, sh);                  \
    acc[0][0] = __builtin_amdgcn_mfma_f32_32x32x16_bf16(ACUR[0][0], b0k0, acc[0][0], 0, 0, 0); \
    acc[0][0] = __builtin_amdgcn_mfma_f32_32x32x16_bf16(ACUR[1][0], b0k1, acc[0][0], 0, 0, 0); \
    acc[0][1] = __builtin_amdgcn_mfma_f32_32x32x16_bf16(ACUR[0][1], b0k0, acc[0][1], 0, 0, 0); \
    acc[0][1] = __builtin_amdgcn_mfma_f32_32x32x16_bf16(ACUR[1][1], b0k1, acc[0][1], 0, 0, 0); \
    acc[1][0] = __builtin_amdgcn_mfma_f32_32x32x16_bf16(ACUR[0][0], b1k0, acc[1][0], 0, 0, 0); \
    acc[1][0] = __builtin_amdgcn_mfma_f32_32x32x16_bf16(ACUR[1][0], b1k1, acc[1][0], 0, 0, 0); \
    acc[1][1] = __builtin_amdgcn_mfma_f32_32x32x16_bf16(ACUR[0][1], b1k0, acc[1][1], 0, 0, 0); \
    acc[1][1] = __builtin_amdgcn_mfma_f32_32x32x16_bf16(ACUR[1][1], b1k1, acc[1][1], 0, 0, 0); }

  for (int g0 = 0; g0 < 2; ++g0){
    const int r0 = g0 * 2;                  // output rows r0, r0+1
    f32x16 acc[2][2];                       // [nr][dt]
    #pragma unroll
    for (int nr = 0; nr < 2; ++nr)
      #pragma unroll
      for (int dt = 0; dt < 2; ++dt) acc[nr][dt] = zero16();

    uint4 s0k0p0, s0k0p1, s0k1p0, s0k1p1;   // window slot 0 (even fy row)
    uint4 s1k0p0, s1k0p1, s1k1p0, s1k1p1;   // window slot 1 (odd fy row)
    short8 aA[2][2], aB[2][2];              // A-frag double buffer [kc][dt]

    LW(0, r0)
    LW(1, r0 + 1)
    LA(aA, 0)

    #pragma unroll 1
    for (int fy2 = 0; fy2 < 32; fy2 += 2){
      CPH(0, 1, aA, aB, fy2 + 1, true)      // fy = fy2   (rows fy2, fy2+1)
      LW(0, r0 + fy2 + 2)
      CPH(1, 0, aB, aA, fy2 + 2, true)      // fy = fy2+1 (rows fy2+1, fy2+2)
      LW(1, r0 + fy2 + 3)
    }
    CPH(0, 1, aA, aB, 0, false)             // fy = 32 (rows 32, 33)

    // column pass: fx = 32, k = fy (0..31)
    #pragma unroll
    for (int nr = 0; nr < 2; ++nr){
      #pragma unroll
      for (int kc = 0; kc < 2; ++kc){
        int base = (r0 + nr + 16 * kc + 8 * h) * 512 + cc * 2;
        u32 v0 = *(const ushort_t*)(ldsc + base + 0 * 512);
        u32 v1 = *(const ushort_t*)(ldsc + base + 1 * 512);
        u32 v2 = *(const ushort_t*)(ldsc + base + 2 * 512);
        u32 v3 = *(const ushort_t*)(ldsc + base + 3 * 512);
        u32 v4 = *(const ushort_t*)(ldsc + base + 4 * 512);
        u32 v5 = *(const ushort_t*)(ldsc + base + 5 * 512);
        u32 v6 = *(const ushort_t*)(ldsc + base + 6 * 512);
        u32 v7 = *(const ushort_t*)(ldsc + base + 7 * 512);
        uint4 t;
        t.x = v0 | (v1 << 16); t.y = v2 | (v3 << 16);
        t.z = v4 | (v5 << 16); t.w = v6 | (v7 << 16);
        short8 Bc = __builtin_bit_cast(short8, t);
        #pragma unroll
        for (int dt = 0; dt < 2; ++dt)
          acc[nr][dt] = __builtin_amdgcn_mfma_f32_32x32x16_bf16(
              acol8[(kc * 2 + dt) * 64 + l], Bc, acc[nr][dt], 0, 0, 0);
      }
    }

    // corner (fy=32, fx=32) + prior-scale + per-pixel best + store.
    // lanes l and l+32: same output column, complementary d-halves ->
    // combine via shfl_xor(32); single writer (h==0).
    #pragma unroll
    for (int nr = 0; nr < 2; ++nr){
      float cv = bf2f((u32)lds16[(r0 + nr + 32) * 256 + cc]);
      float bv = -3e38f; int bd = 0;
      #pragma unroll
      for (int dt = 0; dt < 2; ++dt){
        #pragma unroll
        for (int q = 0; q < 4; ++q){
          f32x4 fc4 = fcp[(dt * 64 + l) * 4 + q];
          f32x4 pr4 = prp[(dt * 64 + l) * 4 + q];
          #pragma unroll
          for (int e = 0; e < 4; ++e){
            int reg = q * 4 + e;
            float s = (acc[nr][dt][reg] + fc4[e] * cv) * pr4[e];
            int d = dt * 32 + e + 8 * q + 4 * h;
            if (s > bv || (s == bv && d < bd)){ bv = s; bd = d; }
          }
        }
      }
      int x = tX + r0 + nr;
      int y = y0 + 8 * c;
      u64 key = ((u64)fsort(bv) << 32) | (u64)(63 - bd);
      u64 other = __shfl_xor(key, 32);
      if (other > key) key = other;
      if (h == 0) pb[(x << 8) | y] = key;
    }
  }
#undef CPH
#undef LW
#undef LA
}

__global__ __launch_bounds__(512) void conv_mfma(
    const float* __restrict__ input,
    const ushort_t* __restrict__ afh, const ushort_t* __restrict__ acolh,
    const float* __restrict__ fcorner, const float* __restrict__ priorR,
    u64* __restrict__ packed)
{
  __shared__ ushort_t lds[9216];           // hi [36][256] bf16, 18 KB
  const int bS = blockIdx.x;               // stripe 0..63
  const int b  = blockIdx.y;
  const int tX = bS * 4;
  const int tid = threadIdx.x;

  const float* inb = input + b * NPIX;
  // conflict-free staging: 16B (8 bf16) per thread-step, contiguous b128 stores
  for (int k = tid; k < 1152; k += 512){   // 36 rows * 32 units
    int r = k >> 5, u = k & 31;
    int gx = (tX - 16 + r) & 255;
    const float* src = inb + (gx << 8) + (u << 3);
    float4 v1 = *(const float4*)(src);
    float4 v2 = *(const float4*)(src + 4);
    uint4 t;
    t.x = rneb(v1.x) | (rneb(v1.y) << 16);
    t.y = rneb(v1.z) | (rneb(v1.w) << 16);
    t.z = rneb(v2.x) | (rneb(v2.y) << 16);
    t.w = rneb(v2.z) | (rneb(v2.w) << 16);
    *(uint4*)((char*)lds + r * 512 + u * 16) = t;
  }
  __syncthreads();

  const int w = tid >> 6, l = tid & 63;
  u64* pb = packed + b * NPIX;
  const int sh = 16 * (w & 1);
  const char* ldsc = (const char*)lds;
  const short8* afh8 = (const short8*)afh;
  const short8* acol8 = (const short8*)acolh;
  const f32x4* fcp = (const f32x4*)fcorner;
  const f32x4* prp = (const f32x4*)priorR;

  switch ((w >> 1) & 3){
    case 0: conv_body<0>(ldsc, lds, w, l, tX, afh8, acol8, fcp, prp, pb, sh); break;
    case 1: conv_body<1>(ldsc, lds, w, l, tX, afh8, acol8, fcp, prp, pb, sh); break;
    case 2: conv_body<2>(ldsc, lds, w, l, tX, afh8, acol8, fcp, prp, pb, sh); break;
    default: conv_body<3>(ldsc, lds, w, l, tX, afh8, acol8, fcp, prp, pb, sh); break;
  }
}

// ---------------- per-batch approx max (parallel) ---------------------------
__global__ __launch_bounds__(256) void bmax_kernel(const u64* __restrict__ packed,
                                                   u32* __restrict__ mmax){
  const int b = blockIdx.y, blk = blockIdx.x, tid = threadIdx.x;
  const u32* ph = (const u32*)(packed + b * NPIX);
  u32 m = 0;
  for (int k = tid; k < 2048; k += 256) m = max(m, ph[2 * (blk * 2048 + k) + 1]);
  __shared__ u32 red[256];
  red[tid] = m; __syncthreads();
  for (int s = 128; s > 0; s >>= 1){
    if (tid < s) red[tid] = max(red[tid], red[tid + s]);
    __syncthreads();
  }
  if (tid == 0) atomicMax(&mmax[b], red[0]);
}

// ---------------- collect candidates within margin of max -------------------
__global__ __launch_bounds__(256) void collect_kernel(const u64* __restrict__ packed,
    const u32* __restrict__ mmax, u32* __restrict__ ncand, u32* __restrict__ cand){
  const int b = blockIdx.y, blk = blockIdx.x, tid = threadIdx.x;
  float M = funsort(mmax[b]);
  u32 tu = fsort(M - MARGIN);
  const u32* ph = (const u32*)(packed + b * NPIX);
  for (int k = tid; k < 2048; k += 256){
    int p = blk * 2048 + k;
    u32 v = ph[2 * p + 1];
    if (v >= tu){
      u32 slot = atomicAdd(ncand, 1u);
      if (slot < CAND_CAP) cand[slot] = ((u32)b << 16) | (u32)p;
    }
  }
}

// ---------------- exact fp32 recompute for candidates, patch map ------------
__global__ __launch_bounds__(64) void rerank_kernel(
    const float* __restrict__ input, const float* __restrict__ filt,
    const float* __restrict__ prior, const u32* __restrict__ ncand,
    const u32* __restrict__ cand, u64* __restrict__ packed)
{
  const int lane = threadIdx.x;            // = d
  int n = (int)min(*ncand, (u32)CAND_CAP);
  const float* fb = filt + lane * 1089;
  float pv = prior[lane];
  for (int i = blockIdx.x; i < n; i += 1024){
    u32 v = cand[i];
    int b = v >> 16, p = v & 0xffff;
    int px = p >> 8, py = p & 255;
    int yc = py - 16;
    float s = 0.f;
    for (int fy = 0; fy < 33; ++fy){
      const float* ir = input + b * NPIX + (((px + fy - 16) & 255) << 8);
      const float* fr = fb + fy * 33;
      for (int fx = 0; fx < 33; ++fx)
        s = fmaf(fr[fx], ir[(yc + fx) & 255], s);
    }
    u64 key = ((u64)fsort(s * pv) << 32) | (u64)(63 - lane);
    #pragma unroll
    for (int off = 32; off; off >>= 1){
      u64 o = __shfl_down(key, off);
      if (o > key) key = o;
    }
    if (lane == 0) packed[b * NPIX + p] = key;
  }
}

// ---------------- fused greedy loop: incremental deadzone -------------------
// 1-exp(-d2/32) == 1.0f exactly for d2 > 554.5 -> picks only perturb 49x49
// patches; 10 discs can't cover the 224x224 interior -> max(u)==1.0 exactly,
// reference normalization is an exact no-op. s = conv*prior*PROD(tmap) in
// registers; per-iter only dirty threads rescan. R10: wave-shfl reduction,
// 2 barriers/iter (was 11 tree barriers on 16 waves).
__global__ __launch_bounds__(1024) void greedy_kernel(
    const u64* __restrict__ packed, const float* __restrict__ prior,
    float* __restrict__ out)
{
  const int b = blockIdx.x;
  const int tid = threadIdx.x;
  const u64* pb = packed + b * NPIX;
  const u32* ph = (const u32*)pb;

  const int x = tid >> 2;                 // owned image row
  const int ybase = (tid & 3) << 6;       // 64-col segment
  const int pbase = (x << 8) + ybase;

  float s[64];
  const bool rowin = (x >= 16 && x < 240);
  #pragma unroll
  for (int i = 0; i < 64; ++i){
    int y = ybase + i;
    float bvv = funsort(ph[2 * (pbase + i) + 1]);
    s[i] = (rowin && y >= 16 && y < 240) ? bvv : 0.0f;
  }
  float tm = -3e38f; int tp = pbase;
  #pragma unroll
  for (int i = 0; i < 64; ++i){
    if (s[i] > tm){ tm = s[i]; tp = pbase + i; }
  }

  __shared__ u64 warr[16];
  __shared__ int spx, spy;
  if (tid == 0){ spx = -100000; spy = -100000; }
  __syncthreads();

  for (int t = 0; t < 10; ++t){
    const int px = spx, py = spy;
    if (px >= 0){
      int dxr = x - px;
      if (dxr >= -24 && dxr <= 24){
        int lo = py - 24 - ybase;
        int hi = py + 24 - ybase;
        if (lo < 64 && hi >= 0){
          float dx2 = (float)(dxr * dxr);
          tm = -3e38f; tp = pbase;
          #pragma unroll
          for (int i = 0; i < 64; ++i){
            if (i >= lo && i <= hi){
              float dy = (float)(ybase + i - py);
              float d2 = dx2 + dy * dy;
              float tmap = 1.f - __expf(d2 * -0.03125f);
              if (d2 <= 16.f) tmap = 0.f;
              s[i] *= tmap;
            }
            if (s[i] > tm){ tm = s[i]; tp = pbase + i; }
          }
        }
      }
    }
    // key: [fsort(value)][~p] -> max = (max value, tie: smallest p)
    u64 key = ((u64)fsort(tm) << 32) | (u64)(0xFFFFu ^ (u32)tp);
    #pragma unroll
    for (int off = 32; off; off >>= 1){
      u64 o = __shfl_down(key, off);
      if (o > key) key = o;
    }
    if ((tid & 63) == 0) warr[tid >> 6] = key;
    __syncthreads();
    if (tid < 64){
      u64 k2 = (tid < 16) ? warr[tid] : 0ull;
      #pragma unroll
      for (int off = 8; off; off >>= 1){
        u64 o = __shfl_down(k2, off);
        if (o > k2) k2 = o;
      }
      if (tid == 0){
        int id = 0xFFFF ^ (int)(k2 & 0xFFFFull);
        float v = funsort((u32)(k2 >> 32));
        u64 pk = pb[id];
        int d = 63 - (int)(pk & 63ull);
        float bvv = funsort((u32)(pk >> 32));
        int xx = id >> 8, yy = id & 255;
        out[b * 30 + t * 3 + 0] = (float)d;
        out[b * 30 + t * 3 + 1] = (float)xx;
        out[b * 30 + t * 3 + 2] = (float)yy;
        out[240 + b * 20 + t * 2 + 0] = v;              // ov0 (umax==1.0 exact)
        out[240 + b * 20 + t * 2 + 1] = bvv / prior[d]; // ov1
        spx = xx; spy = yy;
      }
    }
    __syncthreads();
  }
}

extern "C" void kernel_launch(void* const* d_in, const int* in_sizes, int n_in,
                              void* d_out, int out_size, void* d_ws, size_t ws_size,
                              hipStream_t stream)
{
  const float* input = (const float*)d_in[0];
  const float* filt  = (const float*)d_in[1];
  const float* prior = (const float*)d_in[3];
  float* out = (float*)d_out;

  char* ws = (char*)d_ws;
  u64*      packed  = (u64*)(ws);                    // 4,194,304
  u32*      ncand   = (u32*)  (ws + 4194304);
  u32*      mmax    = (u32*)  (ws + 4194368);        // 32 B
  ushort_t* afh     = (ushort_t*)(ws + 4194432);     // 135,168
  ushort_t* acolh   = (ushort_t*)(ws + 4329600);     // 4,096
  float*    fcorner = (float*)(ws + 4333696);        // 8,192
  float*    priorR  = (float*)(ws + 4341888);        // 8,192
  u32*      cand    = (u32*)  (ws + 4350080);        // 262,144

  prep_kernel<<<64, 256, 0, stream>>>(filt, prior, afh, acolh, fcorner, priorR, ncand, mmax);
  conv_mfma<<<dim3(64, NB), 512, 0, stream>>>(input, afh, acolh, fcorner, priorR, packed);
  bmax_kernel<<<dim3(32, NB), 256, 0, stream>>>(packed, mmax);
  collect_kernel<<<dim3(32, NB), 256, 0, stream>>>(packed, mmax, ncand, cand);
  rerank_kernel<<<1024, 64, 0, stream>>>(input, filt, prior, ncand, cand, packed);
  greedy_kernel<<<NB, 1024, 0, stream>>>(packed, prior, out);
}